// Round 7
// baseline (559.629 us; speedup 1.0000x reference)
//
#include <hip/hip_runtime.h>

// out[e,o,m] = (sum_i basis[e,o,i] * nf[U[e],i,m]) * ew[e, (o==0?0:1), m]
// E=800000, N=50000, D_IN=D_OUT=4, M=32.
//
// R5/R6 diagnosis: 152us kernel is limited by total memory-service BW
// (~1080 MB incl ~385 MB of L3-served gather; ~7.1 TB/s ~= fabric ceiling).
// R7: counting-sort edges into 64-node buckets (prepass ~10us), then a dense
// main kernel: one block per bucket stages the bucket's 32 KB nf slice in LDS
// (nf read once globally, sequential), edges found via packed perm array
// ((u_local<<24)|e). Gather fabric service -> 0. Streams (basis/ew/out) go
// random-at-line-granularity: the decisive test of DRAM random-line efficiency.

typedef float f4 __attribute__((ext_vector_type(4)));

#define BSHIFT 6                  // 64 nodes per bucket -> 32 KB LDS slice
#define BBLK 512                  // main-kernel block size (8 waves)

// ---------- prepass ----------

__global__ void hist_kernel(const int* __restrict__ U, int* __restrict__ hist, int E) {
    int stride = gridDim.x * blockDim.x;
    for (int e = blockIdx.x * blockDim.x + threadIdx.x; e < E; e += stride)
        atomicAdd(&hist[U[e] >> BSHIFT], 1);
}

// single block, 1024 threads; NB <= 1024
__global__ void scan_kernel(int* __restrict__ hist /*[NB+1] -> base*/,
                            int* __restrict__ cursor /*[NB]*/, int NB, int E) {
    __shared__ int a[1024], b[1024];
    int t = threadIdx.x;
    a[t] = (t < NB) ? hist[t] : 0;
    __syncthreads();
    int* src = a; int* dst = b;
    for (int off = 1; off < 1024; off <<= 1) {
        int x = src[t];
        if (t >= off) x += src[t - off];
        dst[t] = x;
        __syncthreads();
        int* tmp = src; src = dst; dst = tmp;
    }
    // src = inclusive scan
    if (t < NB) {
        int excl = (t == 0) ? 0 : src[t - 1];
        hist[t] = excl;        // base[bin]
        cursor[t] = excl;
    }
    if (t == 0) hist[NB] = E;  // base[NB]
}

__global__ void scatter_kernel(const int* __restrict__ U, int* __restrict__ cursor,
                               int* __restrict__ perm, int E) {
    int stride = gridDim.x * blockDim.x;
    for (int e = blockIdx.x * blockDim.x + threadIdx.x; e < E; e += stride) {
        int u = U[e];
        int pos = atomicAdd(&cursor[u >> BSHIFT], 1);
        perm[pos] = ((u & ((1 << BSHIFT) - 1)) << 24) | e;   // e < 2^24
    }
}

// ---------- main: one block per bucket, nf slice in LDS ----------

__global__ __launch_bounds__(BBLK) void equiv_mm_bucket_kernel(
    const float* __restrict__ basis,   // [E,4,4]
    const float* __restrict__ ew,      // [E,2,32]
    const float* __restrict__ nf,      // [N,4,32]
    const int*   __restrict__ base,    // [NB+1]
    const int*   __restrict__ perm,    // [E] packed (u_local<<24)|e
    float*       __restrict__ out,     // [E,4,32]
    int N, int NB)
{
    __shared__ f4 slice[(1 << BSHIFT) * 32];   // 64 nodes x 128 floats = 32 KB
    const f4* nf4 = (const f4*)nf;

    for (int nb = blockIdx.x; nb < NB; nb += gridDim.x) {
        int node0 = nb << BSHIFT;
        int nNodes = min(1 << BSHIFT, N - node0);
        int cnt4 = nNodes * 32;
        __syncthreads();   // previous bucket's readers done before overwrite
        for (int i = threadIdx.x; i < cnt4; i += BBLK)
            slice[i] = __builtin_nontemporal_load(&nf4[(size_t)node0 * 32 + i]);
        __syncthreads();

        int start = base[nb], end = base[nb + 1];
        int lanes = (end - start) << 3;
        for (int k = threadIdx.x; k < lanes; k += BBLK) {
            int slot = start + (k >> 3);
            int m0 = (k & 7) << 2;                       // float offset 0..28
            int pk = __builtin_nontemporal_load(&perm[slot]);
            int e  = pk & 0xFFFFFF;
            int ul = pk >> 24;                           // 0..63

            const f4* xp = slice + ul * 32 + (m0 >> 2);
            f4 x0 = xp[0], x1 = xp[8], x2 = xp[16], x3 = xp[24];

            const f4* bp = (const f4*)(basis + (size_t)e * 16);
            f4 b0 = __builtin_nontemporal_load(bp + 0);
            f4 b1 = __builtin_nontemporal_load(bp + 1);
            f4 b2 = __builtin_nontemporal_load(bp + 2);
            f4 b3 = __builtin_nontemporal_load(bp + 3);

            const f4* wp = (const f4*)(ew + (size_t)e * 64 + m0);
            f4 w0 = __builtin_nontemporal_load(wp + 0);
            f4 w1 = __builtin_nontemporal_load(wp + 8);

            f4* op = (f4*)(out + (size_t)e * 128 + m0);
            __builtin_nontemporal_store((b0.x*x0 + b0.y*x1 + b0.z*x2 + b0.w*x3) * w0, op + 0);
            __builtin_nontemporal_store((b1.x*x0 + b1.y*x1 + b1.z*x2 + b1.w*x3) * w1, op + 8);
            __builtin_nontemporal_store((b2.x*x0 + b2.y*x1 + b2.z*x2 + b2.w*x3) * w1, op + 16);
            __builtin_nontemporal_store((b3.x*x0 + b3.y*x1 + b3.z*x2 + b3.w*x3) * w1, op + 24);
        }
    }
}

// ---------- fallback (R3 structure, 152us) ----------

__global__ __launch_bounds__(256) void equiv_mm_simple_kernel(
    const float* __restrict__ basis, const float* __restrict__ ew,
    const float* __restrict__ nf, const int* __restrict__ U,
    float* __restrict__ out, int E)
{
    int gid = blockIdx.x * blockDim.x + threadIdx.x;
    int e = gid >> 3;
    if (e >= E) return;
    int m0 = (gid & 7) << 2;
    int u = U[e];
    const f4* xp = (const f4*)(nf + (size_t)u * 128 + m0);
    f4 x0 = xp[0], x1 = xp[8], x2 = xp[16], x3 = xp[24];
    const f4* bp = (const f4*)(basis + (size_t)e * 16);
    f4 b0 = bp[0], b1 = bp[1], b2 = bp[2], b3 = bp[3];
    const f4* wp = (const f4*)(ew + (size_t)e * 64 + m0);
    f4 w0 = wp[0], w1 = wp[8];
    f4* op = (f4*)(out + (size_t)e * 128 + m0);
    __builtin_nontemporal_store((b0.x*x0 + b0.y*x1 + b0.z*x2 + b0.w*x3) * w0, op + 0);
    __builtin_nontemporal_store((b1.x*x0 + b1.y*x1 + b1.z*x2 + b1.w*x3) * w1, op + 8);
    __builtin_nontemporal_store((b2.x*x0 + b2.y*x1 + b2.z*x2 + b2.w*x3) * w1, op + 16);
    __builtin_nontemporal_store((b3.x*x0 + b3.y*x1 + b3.z*x2 + b3.w*x3) * w1, op + 24);
}

extern "C" void kernel_launch(void* const* d_in, const int* in_sizes, int n_in,
                              void* d_out, int out_size, void* d_ws, size_t ws_size,
                              hipStream_t stream) {
    const float* basis = (const float*)d_in[0];   // [E,4,4]
    const float* ew    = (const float*)d_in[1];   // [E,2,32]
    const float* nf    = (const float*)d_in[2];   // [N,4,32]
    const int*   U     = (const int*)d_in[3];     // [E]
    float* out = (float*)d_out;

    int E = in_sizes[0] / 16;
    int N = in_sizes[2] / 128;
    int NB = ((N - 1) >> BSHIFT) + 1;             // 782 for N=50000

    // ws layout (ints): base[NB+1] | cursor[NB] | perm[E]
    size_t need = ((size_t)(NB + 1) + NB + E) * 4;
    bool can_sort = (ws_size >= need) && (NB <= 1024) && (E < (1 << 24));

    if (!can_sort) {
        long long total = (long long)E * 8;
        int grid = (int)((total + 255) / 256);
        equiv_mm_simple_kernel<<<grid, 256, 0, stream>>>(basis, ew, nf, U, out, E);
        return;
    }

    int* base   = (int*)d_ws;          // [NB+1], doubles as hist
    int* cursor = base + (NB + 1);     // [NB]
    int* perm   = cursor + NB;         // [E]

    hipMemsetAsync(base, 0, (size_t)(NB + 1) * 4, stream);
    hist_kernel<<<2048, 256, 0, stream>>>(U, base, E);
    scan_kernel<<<1, 1024, 0, stream>>>(base, cursor, NB, E);
    scatter_kernel<<<2048, 256, 0, stream>>>(U, cursor, perm, E);
    equiv_mm_bucket_kernel<<<NB, BBLK, 0, stream>>>(basis, ew, nf, base, perm,
                                                    out, N, NB);
}

// Round 8
// 151.644 us; speedup vs baseline: 3.6904x; 3.6904x over previous
//
#include <hip/hip_runtime.h>

// rep config: E edges, D_IN = D_OUT = 4, M = 32 channels.
// out[e,o,m] = (sum_i basis[e,o,i] * nf[U[e],i,m]) * ew[e, (o==0?0:1), m]
//
// FINAL (revert to R3, best measured 151.95 us):
// 8 lanes per edge, each lane owns a float4 of 4 channels; all loads/stores
// 16B/lane, coalesced within each 8-lane group. Nontemporal stores keep the
// 410 MB write-only output stream out of L2, protecting the nf gather table.
//
// Ceiling argument (R5/R6/R7 counters): mandatory HBM = 695 MB (verified
// zero over-fetch), plus ~385 MB of unavoidable L3-served gather (25.6 MB
// table vs 4 MiB per-XCD L2, unordered edges). Total service 1080 MB at the
// measured ~7.1 TB/s fabric ceiling = ~152 us. Both reordering cures cost
// more than the 385 MB they save (R6 +196 us sparse-lane issue, R7 +408 us
// random-line streams).

typedef float f4 __attribute__((ext_vector_type(4)));

__global__ __launch_bounds__(256) void equiv_mm_kernel(
    const float* __restrict__ basis,   // [E,4,4]
    const float* __restrict__ ew,      // [E,2,32]
    const float* __restrict__ nf,      // [N,4,32]
    const int*   __restrict__ U,       // [E]
    float*       __restrict__ out,     // [E,4,32]
    int E)
{
    int gid = blockIdx.x * blockDim.x + threadIdx.x;
    int e = gid >> 3;
    if (e >= E) return;
    int m0 = (gid & 7) << 2;   // channel offset: 0,4,...,28

    int u = U[e];

    // gather source-node features: rows i=0..3, stride 32 floats (=8 f4)
    const f4* xp = (const f4*)(nf + (size_t)u * 128 + m0);
    f4 x0 = xp[0];
    f4 x1 = xp[8];
    f4 x2 = xp[16];
    f4 x3 = xp[24];

    // per-edge 4x4 basis (broadcast across the 8 lanes of this edge)
    const f4* bp = (const f4*)(basis + (size_t)e * 16);
    f4 b0 = bp[0], b1 = bp[1], b2 = bp[2], b3 = bp[3];

    // radial weights: degree 0 (o=0) and degree 1 (o=1..3)
    const f4* wp = (const f4*)(ew + (size_t)e * 64 + m0);
    f4 w0 = wp[0];
    f4 w1 = wp[8];

    // write-only output stream -> nontemporal (no L2 allocate)
    f4* op = (f4*)(out + (size_t)e * 128 + m0);
    __builtin_nontemporal_store((b0.x * x0 + b0.y * x1 + b0.z * x2 + b0.w * x3) * w0, op + 0);
    __builtin_nontemporal_store((b1.x * x0 + b1.y * x1 + b1.z * x2 + b1.w * x3) * w1, op + 8);
    __builtin_nontemporal_store((b2.x * x0 + b2.y * x1 + b2.z * x2 + b2.w * x3) * w1, op + 16);
    __builtin_nontemporal_store((b3.x * x0 + b3.y * x1 + b3.z * x2 + b3.w * x3) * w1, op + 24);
}

extern "C" void kernel_launch(void* const* d_in, const int* in_sizes, int n_in,
                              void* d_out, int out_size, void* d_ws, size_t ws_size,
                              hipStream_t stream) {
    const float* basis = (const float*)d_in[0];   // [E,4,4]
    const float* ew    = (const float*)d_in[1];   // [E,2,32]
    const float* nf    = (const float*)d_in[2];   // [N,4,32]
    const int*   U     = (const int*)d_in[3];     // [E]
    float* out = (float*)d_out;

    int E = in_sizes[0] / 16;
    long long total = (long long)E * 8;           // 8 lanes per edge
    int block = 256;
    int grid = (int)((total + block - 1) / block);

    equiv_mm_kernel<<<grid, block, 0, stream>>>(basis, ew, nf, U, out, E);
}